// Round 3
// baseline (745.269 us; speedup 1.0000x reference)
//
#include <hip/hip_runtime.h>

#define NN 100000
#define EE 3200000
#define DD 256
#define CC 40
#define UN 16
#define UN2 8

__device__ __forceinline__ float bf2f(unsigned short u) {
    return __uint_as_float(((unsigned int)u) << 16);
}

// Build CSR row_ptr from the sorted adj_row array.
__global__ __launch_bounds__(256) void k_row_ptr(const int* __restrict__ adj_row,
                                                 int* __restrict__ row_ptr) {
    int e = blockIdx.x * 256 + threadIdx.x;
    if (e >= EE) return;
    int r = adj_row[e];
    int prev = (e == 0) ? -1 : adj_row[e - 1];
    for (int rr = prev + 1; rr <= r; ++rr) row_ptr[rr] = e;
    if (e == EE - 1) {
        for (int rr = r + 1; rr <= NN; ++rr) row_ptr[rr] = EE;
    }
}

// x (f32) -> bf16 with RTNE, so the SpMM1 gather moves half the bytes.
__global__ __launch_bounds__(256) void k_cvt(const float* __restrict__ x,
                                             ushort* __restrict__ xb) {
    const int total = NN * DD / 4;
    for (int i = blockIdx.x * 256 + threadIdx.x; i < total; i += gridDim.x * 256) {
        float4 v = ((const float4*)x)[i];
        ushort4 o;
        unsigned int t;
        t = __float_as_uint(v.x); o.x = (unsigned short)((t + 0x7FFFu + ((t >> 16) & 1u)) >> 16);
        t = __float_as_uint(v.y); o.y = (unsigned short)((t + 0x7FFFu + ((t >> 16) & 1u)) >> 16);
        t = __float_as_uint(v.z); o.z = (unsigned short)((t + 0x7FFFu + ((t >> 16) & 1u)) >> 16);
        t = __float_as_uint(v.w); o.w = (unsigned short)((t + 0x7FFFu + ((t >> 16) & 1u)) >> 16);
        ((ushort4*)xb)[i] = o;
    }
}

// Fused SpMM1 + relu + dropout + Linear(256->40), bf16 x-gather.
// One WAVE per row; lane l owns dims [4l..4l+3]. Edge loop in zero-padded
// 16-wide batches (uniform clamped indices) so even the tail stays pipelined.
__global__ __launch_bounds__(256) void k_spmm1_lin(
    const ushort* __restrict__ xb, const float* __restrict__ adj_vals,
    const int* __restrict__ adj_col, const int* __restrict__ row_ptr,
    const float* __restrict__ drop_mask, const float* __restrict__ W,
    const float* __restrict__ b, float* __restrict__ z)
{
    int wave = threadIdx.x >> 6;
    int lane = threadIdx.x & 63;
    int row = blockIdx.x * 4 + wave;   // NN % 4 == 0

    int e0 = __builtin_amdgcn_readfirstlane(row_ptr[row]);
    int e1 = __builtin_amdgcn_readfirstlane(row_ptr[row + 1]);
    const ushort4* xb4 = (const ushort4*)xb;

    float4 acc = {0.f, 0.f, 0.f, 0.f};
    int nb = (e1 - e0 + UN - 1) / UN;
    for (int bI = 0; bI < nb; ++bI) {
        int base = e0 + bI * UN;
        float vv[UN]; int cc[UN];
#pragma unroll
        for (int u = 0; u < UN; ++u) {
            int idx = base + u;
            bool ok = idx < e1;           // wave-uniform
            idx = ok ? idx : e1 - 1;      // clamp: always a valid edge
            vv[u] = ok ? adj_vals[idx] : 0.f;
            cc[u] = adj_col[idx];
        }
        ushort4 xa[UN];
#pragma unroll
        for (int u = 0; u < UN; ++u)
            xa[u] = xb4[(size_t)cc[u] * (DD / 4) + lane];   // 512B/wave gather
#pragma unroll
        for (int u = 0; u < UN; ++u) {
            acc.x = fmaf(vv[u], bf2f(xa[u].x), acc.x);
            acc.y = fmaf(vv[u], bf2f(xa[u].y), acc.y);
            acc.z = fmaf(vv[u], bf2f(xa[u].z), acc.z);
            acc.w = fmaf(vv[u], bf2f(xa[u].w), acc.w);
        }
    }

    // relu + dropout (keep=0.5 -> scale 2)
    float4 mm = ((const float4*)drop_mask)[(size_t)row * (DD / 4) + lane];
    float4 h;
    h.x = fmaxf(acc.x, 0.f) * mm.x * 2.f;
    h.y = fmaxf(acc.y, 0.f) * mm.y * 2.f;
    h.z = fmaxf(acc.z, 0.f) * mm.z * 2.f;
    h.w = fmaxf(acc.w, 0.f) * mm.w * 2.f;

    __shared__ float hs[4][DD];
    ((float4*)hs[wave])[lane] = h;

    // Linear 256->40: lane c (<40) computes the full dot; LDS reads broadcast,
    // W (40KB) is L1/L2-resident.
    if (lane < CC) {
        const float4* wr = (const float4*)(W + (size_t)lane * DD);
        const float4* hv = (const float4*)hs[wave];
        float4 p = {0.f, 0.f, 0.f, 0.f};
#pragma unroll 8
        for (int k = 0; k < DD / 4; ++k) {
            float4 wk = wr[k];
            float4 hk = hv[k];
            p.x = fmaf(hk.x, wk.x, p.x);
            p.y = fmaf(hk.y, wk.y, p.y);
            p.z = fmaf(hk.z, wk.z, p.z);
            p.w = fmaf(hk.w, wk.w, p.w);
        }
        z[(size_t)row * CC + lane] = p.x + p.y + p.z + p.w + b[lane];
    }
}

// out = SpMM(z), z [NN,40] f32 (L2-resident). Zero-padded 8-wide batches.
__global__ __launch_bounds__(256) void k_spmm2(
    const float* __restrict__ z, const float* __restrict__ adj_vals,
    const int* __restrict__ adj_col, const int* __restrict__ row_ptr,
    float* __restrict__ out)
{
    int wave = threadIdx.x >> 6;
    int lane = threadIdx.x & 63;
    int row = blockIdx.x * 4 + wave;
    int cl = lane < CC ? lane : CC - 1;

    int e0 = __builtin_amdgcn_readfirstlane(row_ptr[row]);
    int e1 = __builtin_amdgcn_readfirstlane(row_ptr[row + 1]);

    float acc = 0.f;
    int nb = (e1 - e0 + UN2 - 1) / UN2;
    for (int bI = 0; bI < nb; ++bI) {
        int base = e0 + bI * UN2;
        float vv[UN2]; int cc[UN2];
#pragma unroll
        for (int u = 0; u < UN2; ++u) {
            int idx = base + u;
            bool ok = idx < e1;
            idx = ok ? idx : e1 - 1;
            vv[u] = ok ? adj_vals[idx] : 0.f;
            cc[u] = adj_col[idx];
        }
        float za[UN2];
#pragma unroll
        for (int u = 0; u < UN2; ++u)
            za[u] = z[(size_t)cc[u] * CC + cl];
#pragma unroll
        for (int u = 0; u < UN2; ++u)
            acc = fmaf(vv[u], za[u], acc);
    }
    if (lane < CC) out[(size_t)row * CC + lane] = acc;
}

extern "C" void kernel_launch(void* const* d_in, const int* in_sizes, int n_in,
                              void* d_out, int out_size, void* d_ws, size_t ws_size,
                              hipStream_t stream) {
    const float* x         = (const float*)d_in[0];
    const float* adj_vals  = (const float*)d_in[1];
    const float* W         = (const float*)d_in[2];
    const float* b         = (const float*)d_in[3];
    const float* drop_mask = (const float*)d_in[4];
    const int*   adj_row   = (const int*)d_in[5];
    const int*   adj_col   = (const int*)d_in[6];
    float* out = (float*)d_out;

    // ws: row_ptr [(NN+1) i32] | z [NN*CC f32] | xb [NN*DD bf16]
    char* wsp = (char*)d_ws;
    int* row_ptr = (int*)wsp;
    size_t rp_bytes = ((size_t)(NN + 1) * 4 + 255) & ~(size_t)255;
    float* zbuf = (float*)(wsp + rp_bytes);
    size_t z_bytes = (size_t)NN * CC * 4;
    ushort* xb = (ushort*)(wsp + rp_bytes + z_bytes);

    hipLaunchKernelGGL(k_row_ptr, dim3((EE + 255) / 256), dim3(256), 0, stream,
                       adj_row, row_ptr);
    hipLaunchKernelGGL(k_cvt, dim3(1024), dim3(256), 0, stream, x, xb);
    hipLaunchKernelGGL(k_spmm1_lin, dim3(NN / 4), dim3(256), 0, stream,
                       xb, adj_vals, adj_col, row_ptr, drop_mask, W, b, zbuf);
    hipLaunchKernelGGL(k_spmm2, dim3(NN / 4), dim3(256), 0, stream,
                       zbuf, adj_vals, adj_col, row_ptr, out);
}